// Round 19
// baseline (380.421 us; speedup 1.0000x reference)
//
#include <hip/hip_runtime.h>

#define N_NODES 50000
#define N_EDGES 800000
#define NBUCKET 391        // key = dst>>7; 128 nodes per bucket; 391*128 = 50048
#define BNODES 128
#define CAP 4096           // edges per bucket (mean 2048)
#define NCHUNK 256         // bin blocks; 800000 = 256*3125
#define CE 3125
#define NCVT 400000        // N_NODES*64/8 uint4 convert groups
#define LHP 68             // lh row stride in dwords (16B-aligned, bank-spread: 68%32=4)

typedef short bf16x8 __attribute__((ext_vector_type(8)));
typedef float f32x4 __attribute__((ext_vector_type(4)));

__device__ __forceinline__ unsigned short f2bf(float f) {
    unsigned int u = __float_as_uint(f);
    unsigned int r = (u + 0x7fffu + ((u >> 16) & 1u)) >> 16;
    return (unsigned short)r;
}
__device__ __forceinline__ float bflo(unsigned int u) { return __uint_as_float(u << 16); }
__device__ __forceinline__ float bfhi(unsigned int u) { return __uint_as_float(u & 0xffff0000u); }

// ---------------------------------------------------------------------------
// Kernel 1: radix bin by dst>>7 + bf16 convert. 4-copy LDS histogram (one
// per wave, quarters same-address LDS-atomic serialization); one global
// atomic per (block,bucket) reserves a range; pairs written in runs.
// ---------------------------------------------------------------------------
__global__ __launch_bounds__(256)
void gcn_bin(const int* __restrict__ src, const int* __restrict__ dst,
             const float4* __restrict__ x4,
             unsigned int* __restrict__ pbuf, int* __restrict__ gcur,
             uint4* __restrict__ xb) {
    __shared__ int hist[4][NBUCKET];
    __shared__ int wpre[4][NBUCKET];
    __shared__ int gbase[NBUCKET];
    int tid = threadIdx.x;
    int wid = tid >> 6;
    int chunk = blockIdx.x;
    for (int i = tid; i < 4 * NBUCKET; i += 256) ((int*)hist)[i] = 0;
    __syncthreads();

    int lo = chunk * CE;
    unsigned int pairr[13];
    unsigned int kp[13];          // key<<16 | local pos (per-wave)
#pragma unroll
    for (int j = 0; j < 13; ++j) {
        int off = tid + j * 256;
        kp[j] = 0xFFFFFFFFu;
        if (off < CE) {
            int d = dst[lo + off];
            int s = src[lo + off];
            int key = d >> 7;
            int pos = atomicAdd(&hist[wid][key], 1);
            pairr[j] = ((unsigned int)d << 16) | (unsigned int)s;
            kp[j] = ((unsigned int)key << 16) | (unsigned int)pos;
        }
    }
    __syncthreads();
    for (int i = tid; i < NBUCKET; i += 256) {
        int c0 = hist[0][i], c1 = hist[1][i];
        int c2 = hist[2][i], c3 = hist[3][i];
        wpre[0][i] = 0;
        wpre[1][i] = c0;
        wpre[2][i] = c0 + c1;
        wpre[3][i] = c0 + c1 + c2;
        gbase[i] = atomicAdd(&gcur[i], c0 + c1 + c2 + c3);
    }
    __syncthreads();
#pragma unroll
    for (int j = 0; j < 13; ++j) {
        if (kp[j] != 0xFFFFFFFFu) {
            int key = (int)(kp[j] >> 16);
            int idx = gbase[key] + wpre[wid][key] + (int)(kp[j] & 0xFFFFu);
            if (idx < CAP) pbuf[key * CAP + idx] = pairr[j];
        }
    }

    // fused bf16 convert (grid-stride over 400000 uint4 groups)
    for (int i = chunk * 256 + tid; i < NCVT; i += NCHUNK * 256) {
        float4 a = x4[i * 2];
        float4 c = x4[i * 2 + 1];
        uint4 o;
        o.x = (unsigned)f2bf(a.x) | ((unsigned)f2bf(a.y) << 16);
        o.y = (unsigned)f2bf(a.z) | ((unsigned)f2bf(a.w) << 16);
        o.z = (unsigned)f2bf(c.x) | ((unsigned)f2bf(c.y) << 16);
        o.w = (unsigned)f2bf(c.z) | ((unsigned)f2bf(c.w) << 16);
        xb[i] = o;
    }
}

// ---------------------------------------------------------------------------
// Kernel 2: FUSED scatter-accumulate + mean + MFMA linear. One block per
// bucket (128 nodes, ~2048 edges). 8 lanes per edge, each lane loads a
// uint4 (8 bf16 dims, full 128B row per edge), converts, and accumulates
// into the LDS f32 h-tile via ds_add_f32 (row stride 68 dwords: 16B-aligned
// and 68%32=4 spreads banks across rows). Degree counted in LDS. No ELL,
// no global h round-trip. After barrier: 8 x 16-row MFMA tiles (2 per
// wave), A = lh * inv(deg) converted inline, B = W (L2-hot) converted
// inline. D layout: col=lane&15, row=(lane>>4)*4+r (R9/R10-verified).
// ---------------------------------------------------------------------------
__global__ __launch_bounds__(256)
void gcn_fused(const uint4* __restrict__ xb4,
               const unsigned int* __restrict__ pbuf,
               const int* __restrict__ gcur,
               const float* __restrict__ W,
               const float* __restrict__ b,
               float* __restrict__ out) {
    __shared__ float lh[BNODES][LHP];   // 34.8KB
    __shared__ int lcnt[BNODES];
    int tid = threadIdx.x;
    int lane = tid & 63;
    int w = tid >> 6;
    int key = blockIdx.x;

    float* lz = &lh[0][0];
    for (int i = tid; i < BNODES * LHP; i += 256) lz[i] = 0.f;
    if (tid < BNODES) lcnt[tid] = 0;
    __syncthreads();

    int m = min(gcur[key], CAP);
    int base = key * CAP;
    int eg = lane >> 3;    // edge subgroup 0..7
    int col = lane & 7;    // uint4 column (8 bf16 dims)

    for (int ib = w * 8; ib < m; ib += 32) {
        int e = ib + eg;
        if (e < m) {
            unsigned int u = pbuf[base + e];
            int dl = (int)(u >> 16) & (BNODES - 1);
            int s = (int)(u & 0xFFFFu);
            uint4 v = xb4[s * 8 + col];    // row = 64 bf16 = 8 uint4
            float* hp = &lh[dl][col * 8];
            atomicAdd(hp + 0, bflo(v.x));
            atomicAdd(hp + 1, bfhi(v.x));
            atomicAdd(hp + 2, bflo(v.y));
            atomicAdd(hp + 3, bfhi(v.y));
            atomicAdd(hp + 4, bflo(v.z));
            atomicAdd(hp + 5, bfhi(v.z));
            atomicAdd(hp + 6, bflo(v.w));
            atomicAdd(hp + 7, bfhi(v.w));
            if (col == 0) atomicAdd(&lcnt[dl], 1);
        }
    }
    __syncthreads();

    // ---- MFMA epilogue: 8 tiles of 16 rows, waves take tt = w, w+4 ----
    int row = lane & 15;
    int quad = lane >> 4;

    bf16x8 bfrag[4][2];
#pragma unroll
    for (int nt = 0; nt < 4; ++nt) {
#pragma unroll
        for (int kc = 0; kc < 2; ++kc) {
            const float* wp = &W[(nt * 16 + row) * 64 + kc * 32 + quad * 8];
            float4 w0 = *(const float4*)wp;
            float4 w1 = *(const float4*)(wp + 4);
            bf16x8 f;
            f[0] = (short)f2bf(w0.x); f[1] = (short)f2bf(w0.y);
            f[2] = (short)f2bf(w0.z); f[3] = (short)f2bf(w0.w);
            f[4] = (short)f2bf(w1.x); f[5] = (short)f2bf(w1.y);
            f[6] = (short)f2bf(w1.z); f[7] = (short)f2bf(w1.w);
            bfrag[nt][kc] = f;
        }
    }

    for (int tt = w; tt < 8; tt += 4) {
        int r = tt * 16 + row;             // local row (A row for this lane)
        int c = lcnt[r];
        float inv = c > 0 ? 1.0f / (float)c : 0.0f;

        bf16x8 afrag[2];
#pragma unroll
        for (int kc = 0; kc < 2; ++kc) {
            const float* hp = &lh[r][kc * 32 + quad * 8];
            bf16x8 f;
#pragma unroll
            for (int j = 0; j < 8; ++j) f[j] = (short)f2bf(hp[j] * inv);
            afrag[kc] = f;
        }

        f32x4 d[4] = {{0.f, 0.f, 0.f, 0.f}, {0.f, 0.f, 0.f, 0.f},
                      {0.f, 0.f, 0.f, 0.f}, {0.f, 0.f, 0.f, 0.f}};
#pragma unroll
        for (int nt = 0; nt < 4; ++nt) {
#pragma unroll
            for (int kc = 0; kc < 2; ++kc) {
                d[nt] = __builtin_amdgcn_mfma_f32_16x16x32_bf16(
                    afrag[kc], bfrag[nt][kc], d[nt], 0, 0, 0);
            }
        }

        int gb = key * BNODES + tt * 16;   // global node base for this tile
#pragma unroll
        for (int nt = 0; nt < 4; ++nt) {
            float bias = b[nt * 16 + row];
#pragma unroll
            for (int rr = 0; rr < 4; ++rr) {
                int node = gb + quad * 4 + rr;
                if (node < N_NODES)
                    out[node * 64 + nt * 16 + row] = d[nt][rr] + bias;
            }
        }
    }
}

extern "C" void kernel_launch(void* const* d_in, const int* in_sizes, int n_in,
                              void* d_out, int out_size, void* d_ws, size_t ws_size,
                              hipStream_t stream) {
    const float* x   = (const float*)d_in[0];
    const int*   src = (const int*)d_in[1];
    const int*   dst = (const int*)d_in[2];
    const float* W   = (const float*)d_in[3];
    const float* b   = (const float*)d_in[4];
    float* out = (float*)d_out;

    unsigned int* pbuf = (unsigned int*)d_ws;                 // 391*4096 u32 (6.4MB)
    int* gcur = (int*)(pbuf + (size_t)NBUCKET * CAP);         // 512 ints
    unsigned short* xb = (unsigned short*)(gcur + 512);       // 50000*64 u16 (6.4MB)

    hipMemsetAsync(gcur, 0, 512 * sizeof(int), stream);
    gcn_bin<<<NCHUNK, 256, 0, stream>>>(src, dst, (const float4*)x,
                                        pbuf, gcur, (uint4*)xb);
    gcn_fused<<<NBUCKET, 256, 0, stream>>>(
        (const uint4*)xb, pbuf, gcur, W, b, out);
}

// Round 20
// 65.426 us; speedup vs baseline: 5.8145x; 5.8145x over previous
//
#include <hip/hip_runtime.h>

#define N_NODES 50000
#define N_EDGES 800000
#define SLOTS 64           // max degree kept per node
#define ZROW 50000         // dummy node id -> zeroed xb row (ELL padding)
#define XROWS 50048        // xb rows incl. zero row
#define NBUCKET 196        // key = dst>>8; 256 nodes per bucket; 196*256 = 50176
#define BNODES 256
#define CAP 8192           // edges per bucket (mean 4082)
#define NCHUNK 256         // bin blocks; 800000 = 256*3125
#define CE 3125
#define NCVT 400000        // N_NODES*64/8 uint4 convert groups
#define NTILES 3125        // 50000/16 nodes per fused tile (exact)
#define ELLC_CAP 1152000   // >= 800000 + 50176*7 (hard bound on padded slots)

typedef short bf16x8 __attribute__((ext_vector_type(8)));
typedef float f32x4 __attribute__((ext_vector_type(4)));

__device__ __forceinline__ unsigned short f2bf(float f) {
    unsigned int u = __float_as_uint(f);
    unsigned int r = (u + 0x7fffu + ((u >> 16) & 1u)) >> 16;
    return (unsigned short)r;
}
__device__ __forceinline__ float bflo(unsigned int u) { return __uint_as_float(u << 16); }
__device__ __forceinline__ float bfhi(unsigned int u) { return __uint_as_float(u & 0xffff0000u); }

// ---------------------------------------------------------------------------
// Kernel 1: radix bin by dst>>8 + bf16 convert (R16/R18-proven). 4-copy LDS
// histogram; one global atomic per (block,bucket); pairs written in runs.
// Also zeroes the dummy xb row.
// ---------------------------------------------------------------------------
__global__ __launch_bounds__(256)
void gcn_bin(const int* __restrict__ src, const int* __restrict__ dst,
             const float4* __restrict__ x4,
             unsigned int* __restrict__ pbuf, int* __restrict__ gcur,
             uint4* __restrict__ xb) {
    __shared__ int hist[4][NBUCKET];
    __shared__ int wpre[4][NBUCKET];
    __shared__ int gbase[NBUCKET];
    int tid = threadIdx.x;
    int wid = tid >> 6;
    int chunk = blockIdx.x;
    for (int i = tid; i < 4 * NBUCKET; i += 256) ((int*)hist)[i] = 0;
    __syncthreads();

    int lo = chunk * CE;
    unsigned int pairr[13];
    unsigned int kp[13];          // key<<16 | local pos (per-wave)
#pragma unroll
    for (int j = 0; j < 13; ++j) {
        int off = tid + j * 256;
        kp[j] = 0xFFFFFFFFu;
        if (off < CE) {
            int d = dst[lo + off];
            int s = src[lo + off];
            int key = d >> 8;
            int pos = atomicAdd(&hist[wid][key], 1);
            pairr[j] = ((unsigned int)d << 16) | (unsigned int)s;
            kp[j] = ((unsigned int)key << 16) | (unsigned int)pos;
        }
    }
    __syncthreads();
    if (tid < NBUCKET) {
        int c0 = hist[0][tid], c1 = hist[1][tid];
        int c2 = hist[2][tid], c3 = hist[3][tid];
        wpre[0][tid] = 0;
        wpre[1][tid] = c0;
        wpre[2][tid] = c0 + c1;
        wpre[3][tid] = c0 + c1 + c2;
        gbase[tid] = atomicAdd(&gcur[tid], c0 + c1 + c2 + c3);
    }
    __syncthreads();
#pragma unroll
    for (int j = 0; j < 13; ++j) {
        if (kp[j] != 0xFFFFFFFFu) {
            int key = (int)(kp[j] >> 16);
            int idx = gbase[key] + wpre[wid][key] + (int)(kp[j] & 0xFFFFu);
            if (idx < CAP) pbuf[key * CAP + idx] = pairr[j];
        }
    }

    // zero the dummy row (ELL padding target)
    int gi = chunk * 256 + tid;
    if (gi < 8) xb[(size_t)ZROW * 8 + gi] = make_uint4(0u, 0u, 0u, 0u);

    // fused bf16 convert (grid-stride over 400000 uint4 groups)
    for (int i = gi; i < NCVT; i += NCHUNK * 256) {
        float4 a = x4[i * 2];
        float4 c = x4[i * 2 + 1];
        uint4 o;
        o.x = (unsigned)f2bf(a.x) | ((unsigned)f2bf(a.y) << 16);
        o.y = (unsigned)f2bf(a.z) | ((unsigned)f2bf(a.w) << 16);
        o.z = (unsigned)f2bf(c.x) | ((unsigned)f2bf(c.y) << 16);
        o.w = (unsigned)f2bf(c.z) | ((unsigned)f2bf(c.w) << 16);
        xb[i] = o;
    }
}

// ---------------------------------------------------------------------------
// Kernel 2: build COMPACT padded-CSR in LDS. Scatter into LDS ELL as before
// (pad-prefilled with ZROW), then per-node padded len pl=(deg+7)&~7, block
// prefix-sum, ONE cursor atomic per block, contiguous compact dump (2.3MB
// total vs 6.4MB full ELL). offs[node] u32 + deg[node] u16.
// ---------------------------------------------------------------------------
__global__ __launch_bounds__(256)
void gcn_build(const unsigned int* __restrict__ pbuf,
               const int* __restrict__ gcur, int* __restrict__ ecur,
               unsigned short* __restrict__ ellc,
               unsigned int* __restrict__ offs,
               unsigned short* __restrict__ deg) {
    __shared__ int cnt[BNODES];
    __shared__ unsigned short lell[BNODES * SLOTS];   // 32KB
    __shared__ int lpre[BNODES];
    __shared__ int gbaseS;
    int key = blockIdx.x;
    int tid = threadIdx.x;
    cnt[tid] = 0;
    uint4* lf = (uint4*)lell;
    const uint4 pad = make_uint4(0xC350C350u, 0xC350C350u, 0xC350C350u, 0xC350C350u);
    for (int i = tid; i < BNODES * SLOTS / 8; i += 256) lf[i] = pad;
    __syncthreads();

    int m = min(gcur[key], CAP);
    int base = key * CAP;
    for (int i = tid; i < m; i += 256) {
        unsigned int u = pbuf[base + i];
        int dl = (int)(u >> 16) & 255;
        int pos = atomicAdd(&cnt[dl], 1);
        if (pos < SLOTS) lell[dl * SLOTS + pos] = (unsigned short)(u & 0xFFFFu);
    }
    __syncthreads();

    int c = min(cnt[tid], SLOTS);
    int pl = (c + 7) & ~7;
    lpre[tid] = pl;
    __syncthreads();
    for (int off = 1; off < 256; off <<= 1) {
        int v = (tid >= off) ? lpre[tid - off] : 0;
        __syncthreads();
        lpre[tid] += v;
        __syncthreads();
    }
    if (tid == 255) gbaseS = atomicAdd(ecur, lpre[255]);
    __syncthreads();
    int gb = gbaseS + lpre[tid] - pl;

    offs[key * BNODES + tid] = (unsigned int)gb;
    deg[key * BNODES + tid] = (unsigned short)c;

    const uint4* lsrc = (const uint4*)&lell[tid * SLOTS];
    uint4* gdst = (uint4*)&ellc[gb];
    for (int j = 0; j < (pl >> 3); ++j) gdst[j] = lsrc[j];
}

// ---------------------------------------------------------------------------
// Kernel 3: FUSED gather-mean + MFMA linear (R18 structure, compact ELL,
// all-wave epilogue). Block = 16-node tile; wave w gathers nodes w*4+i via
// the 8-subgroup branch-free loop, h rows -> padded LDS tile. Epilogue:
// wave w computes output-column block nt=w (2 MFMAs), so all 4 waves work.
// D layout: col=lane&15, row=(lane>>4)*4+r (R9/R10-verified).
// ---------------------------------------------------------------------------
__global__ __launch_bounds__(256)
void gcn_gather_gemm(const uint4* __restrict__ xb4,
                     const unsigned int* __restrict__ offs,
                     const unsigned short* __restrict__ deg,
                     const unsigned short* __restrict__ ellc,
                     const float* __restrict__ W,
                     const float* __restrict__ b,
                     float* __restrict__ out) {
    __shared__ uint4 lh[16][9];   // 16 h rows (8 uint4 each) + 1 pad
    int tid = threadIdx.x;
    int lane = tid & 63;
    int w = tid >> 6;
    int tile = blockIdx.x;
    int g = lane >> 3;     // edge subgroup 0..7
    int col = lane & 7;    // uint4 column (8 bf16 dims)

#pragma unroll
    for (int i = 0; i < 4; ++i) {
        int node = tile * 16 + w * 4 + i;
        int c = (int)deg[node];
        int cr = (c + 7) & ~7;
        unsigned int off = offs[node];
        int myid = (lane < cr) ? (int)ellc[off + lane] : ZROW;

        float a0 = 0.f, a1 = 0.f, a2 = 0.f, a3 = 0.f;
        float a4 = 0.f, a5 = 0.f, a6 = 0.f, a7 = 0.f;
        for (int k = 0; k < cr; k += 8) {
            int sid = __shfl(myid, k + g, 64);
            uint4 v = xb4[sid * 8 + col];   // row = 64 bf16 = 8 uint4
            a0 += bflo(v.x); a1 += bfhi(v.x);
            a2 += bflo(v.y); a3 += bfhi(v.y);
            a4 += bflo(v.z); a5 += bfhi(v.z);
            a6 += bflo(v.w); a7 += bfhi(v.w);
        }
#pragma unroll
        for (int off2 = 8; off2 < 64; off2 <<= 1) {
            a0 += __shfl_xor(a0, off2, 64); a1 += __shfl_xor(a1, off2, 64);
            a2 += __shfl_xor(a2, off2, 64); a3 += __shfl_xor(a3, off2, 64);
            a4 += __shfl_xor(a4, off2, 64); a5 += __shfl_xor(a5, off2, 64);
            a6 += __shfl_xor(a6, off2, 64); a7 += __shfl_xor(a7, off2, 64);
        }
        if (g == 0) {
            float inv = c > 0 ? 1.0f / (float)c : 0.0f;
            uint4 o;
            o.x = (unsigned)f2bf(a0 * inv) | ((unsigned)f2bf(a1 * inv) << 16);
            o.y = (unsigned)f2bf(a2 * inv) | ((unsigned)f2bf(a3 * inv) << 16);
            o.z = (unsigned)f2bf(a4 * inv) | ((unsigned)f2bf(a5 * inv) << 16);
            o.w = (unsigned)f2bf(a6 * inv) | ((unsigned)f2bf(a7 * inv) << 16);
            lh[w * 4 + i][col] = o;
        }
    }
    __syncthreads();

    // ---- MFMA epilogue: wave w owns output-column block nt = w ----
    int row = lane & 15;
    int quad = lane >> 4;
    int base = tile * 16;
    int nt = w;

    bf16x8 bfrag[2];
#pragma unroll
    for (int kc = 0; kc < 2; ++kc) {
        const float* wp = &W[(nt * 16 + row) * 64 + kc * 32 + quad * 8];
        float4 w0 = *(const float4*)wp;
        float4 w1 = *(const float4*)(wp + 4);
        bf16x8 f;
        f[0] = (short)f2bf(w0.x); f[1] = (short)f2bf(w0.y);
        f[2] = (short)f2bf(w0.z); f[3] = (short)f2bf(w0.w);
        f[4] = (short)f2bf(w1.x); f[5] = (short)f2bf(w1.y);
        f[6] = (short)f2bf(w1.z); f[7] = (short)f2bf(w1.w);
        bfrag[kc] = f;
    }

    bf16x8 afrag[2];
#pragma unroll
    for (int kc = 0; kc < 2; ++kc) {
        uint4 av = lh[row][kc * 4 + quad];
        afrag[kc] = *(const bf16x8*)&av;
    }

    f32x4 d = {0.f, 0.f, 0.f, 0.f};
#pragma unroll
    for (int kc = 0; kc < 2; ++kc) {
        d = __builtin_amdgcn_mfma_f32_16x16x32_bf16(afrag[kc], bfrag[kc], d, 0, 0, 0);
    }

    float bias = b[nt * 16 + row];
#pragma unroll
    for (int rr = 0; rr < 4; ++rr) {
        out[(base + quad * 4 + rr) * 64 + nt * 16 + row] = d[rr] + bias;
    }
}

extern "C" void kernel_launch(void* const* d_in, const int* in_sizes, int n_in,
                              void* d_out, int out_size, void* d_ws, size_t ws_size,
                              hipStream_t stream) {
    const float* x   = (const float*)d_in[0];
    const int*   src = (const int*)d_in[1];
    const int*   dst = (const int*)d_in[2];
    const float* W   = (const float*)d_in[3];
    const float* b   = (const float*)d_in[4];
    float* out = (float*)d_out;

    unsigned int* pbuf = (unsigned int*)d_ws;                 // 196*8192 u32 (6.4MB)
    int* gcur = (int*)(pbuf + (size_t)NBUCKET * CAP);         // 512 ints (incl. ecur)
    int* ecur = gcur + 256;                                   // compact-ELL cursor
    unsigned int* offs = (unsigned int*)(gcur + 512);         // 50176 u32
    unsigned short* deg = (unsigned short*)(offs + NBUCKET * BNODES); // 50176 u16
    unsigned short* ellc = deg + NBUCKET * BNODES;            // 1152000 u16 (2.3MB)
    unsigned short* xb = ellc + ELLC_CAP;                     // 50048*64 u16 (6.4MB)

    hipMemsetAsync(gcur, 0, 512 * sizeof(int), stream);
    gcn_bin<<<NCHUNK, 256, 0, stream>>>(src, dst, (const float4*)x,
                                        pbuf, gcur, (uint4*)xb);
    gcn_build<<<NBUCKET, 256, 0, stream>>>(pbuf, gcur, ecur, ellc, offs, deg);
    gcn_gather_gemm<<<NTILES, 256, 0, stream>>>(
        (const uint4*)xb, offs, deg, ellc, W, b, out);
}